// Round 2
// baseline (965.751 us; speedup 1.0000x reference)
//
#include <hip/hip_runtime.h>
#include <cstdio>

typedef unsigned short u16;
typedef float f32x4 __attribute__((ext_vector_type(4)));
typedef __bf16 bf16x8 __attribute__((ext_vector_type(8)));
typedef u16 u16x8 __attribute__((ext_vector_type(8)));
typedef u16 u16x4 __attribute__((ext_vector_type(4)));

__device__ __forceinline__ u16 f2bf(float x) {
  unsigned u = __float_as_uint(x);
  u = (u + 0x7FFFu + ((u >> 16) & 1u)) >> 16;
  return (u16)u;
}

__device__ __forceinline__ f32x4 mfma_bf16(bf16x8 a, bf16x8 b, f32x4 c) {
  return __builtin_amdgcn_mfma_f32_16x16x32_bf16(a, b, c, 0, 0, 0);
}

// async global->LDS, 16B per lane. LDS dest = wave-uniform base + lane*16.
__device__ __forceinline__ void gload_lds16(const void* g, void* l) {
  __builtin_amdgcn_global_load_lds(
      (const __attribute__((address_space(1))) void*)g,
      (__attribute__((address_space(3))) void*)l, 16, 0, 0);
}

// C[m,n] = scale * sum_k A[m,k] * B[n,k]   (both operands K-contiguous)
// 128x128 tile, BK=64, 256 threads (4 waves, 2x2 wave grid, 4x4 16x16 frags each)
// Staging via global_load_lds width=16: per wave, 4 calls/tile each for A and B.
template <bool BF16OUT, bool SKIP_UPPER, bool KLIMIT>
__global__ __launch_bounds__(256) void gemm_bt(
    const u16* __restrict__ A, const u16* __restrict__ B, void* __restrict__ Cv,
    int K, int lda, int ldb, int ldc,
    long long sAz, long long sBz, long long sCz, float scale)
{
  const int n0 = blockIdx.x * 128;
  const int m0 = blockIdx.y * 128;
  if (SKIP_UPPER && n0 > m0 + 127) return;  // fully-masked score tile (s > t everywhere)
  const int z = blockIdx.z;
  A += (long long)z * sAz;
  B += (long long)z * sBz;

  const int tid = threadIdx.x;
  const int wave = tid >> 6, lane = tid & 63;

  __shared__ u16 lA[128 * 64];
  __shared__ u16 lB[128 * 64];

  f32x4 acc[4][4] = {};

  int kEnd = K;
  if (KLIMIT) { int ke = n0 + 128; kEnd = ke < K ? ke : K; }  // P[t,s]==0 for s>t

  // per-lane global source for staging; LDS layout row-major [128][64],
  // lane l of wave w covers row (w*32 + l/8), cols (l&7)*8 .. +8
  const int srow = wave * 32 + (lane >> 3);
  const int scol = (lane & 7) * 8;
  const u16* gA = A + (long long)(m0 + srow) * lda + scol;
  const u16* gB = B + (long long)(n0 + srow) * ldb + scol;
  const int ldsBase = wave * 2048;  // wave-uniform element offset; HW adds lane*16B

  const int wm = (wave >> 1) * 64, wn = (wave & 1) * 64;
  const int frow = lane & 15, fk = (lane >> 4) * 8;

  for (int k0 = 0; k0 < kEnd; k0 += 64) {
    __syncthreads();  // previous compute done before overwriting LDS
#pragma unroll
    for (int i = 0; i < 4; ++i) {
      gload_lds16(gA + (long long)i * 8 * lda + k0, &lA[ldsBase + i * 512]);
      gload_lds16(gB + (long long)i * 8 * ldb + k0, &lB[ldsBase + i * 512]);
    }
    __syncthreads();  // vmcnt(0) drained by compiler before barrier -> tile ready
#pragma unroll
    for (int kk = 0; kk < 64; kk += 32) {
      bf16x8 af[4], bfr[4];
#pragma unroll
      for (int m = 0; m < 4; ++m)
        af[m] = *(const bf16x8*)(&lA[(wm + m * 16 + frow) * 64 + kk + fk]);
#pragma unroll
      for (int n = 0; n < 4; ++n)
        bfr[n] = *(const bf16x8*)(&lB[(wn + n * 16 + frow) * 64 + kk + fk]);
#pragma unroll
      for (int m = 0; m < 4; ++m)
#pragma unroll
        for (int n = 0; n < 4; ++n)
          acc[m][n] = mfma_bf16(af[m], bfr[n], acc[m][n]);
    }
  }

  // C/D layout: col = lane&15, row = (lane>>4)*4 + r  [m89-verified]
  const int crow0 = m0 + wm + (lane >> 4) * 4;
  const int ccol0 = n0 + wn + (lane & 15);
  if (BF16OUT) {
    u16* C = (u16*)Cv + (long long)z * sCz;
#pragma unroll
    for (int m = 0; m < 4; ++m)
#pragma unroll
      for (int n = 0; n < 4; ++n)
#pragma unroll
        for (int r = 0; r < 4; ++r)
          C[(long long)(crow0 + m * 16 + r) * ldc + ccol0 + n * 16] = f2bf(acc[m][n][r] * scale);
  } else {
    float* C = (float*)Cv + (long long)z * sCz;
#pragma unroll
    for (int m = 0; m < 4; ++m)
#pragma unroll
      for (int n = 0; n < 4; ++n)
#pragma unroll
        for (int r = 0; r < 4; ++r)
          C[(long long)(crow0 + m * 16 + r) * ldc + ccol0 + n * 16] = acc[m][n][r] * scale;
  }
}

// (b, i, s) fp32  ->  (b, s, i) bf16 ; one 64x64 tile per block, block (64,4)
__global__ __launch_bounds__(256) void conv_transpose(const float* __restrict__ src, u16* __restrict__ dst)
{
  const int b = blockIdx.z;
  const float* s = src + (long long)b * 1024 * 2048;
  u16* d = dst + (long long)b * 2048 * 1024;
  const int s0 = blockIdx.x * 64, i0 = blockIdx.y * 64;
  const int tx = threadIdx.x, ty = threadIdx.y;
  __shared__ float tile[64][65];
#pragma unroll
  for (int r = 0; r < 16; ++r)
    tile[r * 4 + ty][tx] = s[(long long)(i0 + r * 4 + ty) * 2048 + s0 + tx];
  __syncthreads();
#pragma unroll
  for (int r = 0; r < 16; ++r)
    d[(long long)(s0 + r * 4 + ty) * 1024 + i0 + tx] = f2bf(tile[tx][r * 4 + ty]);
}

__global__ __launch_bounds__(256) void conv_weights(
    const float* __restrict__ a, const float* __restrict__ b, const float* __restrict__ c,
    u16* __restrict__ oa, u16* __restrict__ ob, u16* __restrict__ oc)
{
  const int which = blockIdx.y;
  const float* s = which == 0 ? a : which == 1 ? b : c;
  u16* d = which == 0 ? oa : which == 1 ? ob : oc;
  const int idx = (blockIdx.x * 256 + threadIdx.x) * 4;
  f32x4 v = *(const f32x4*)(s + idx);
  u16x4 o;
#pragma unroll
  for (int j = 0; j < 4; ++j) o[j] = f2bf(v[j]);
  *(u16x4*)(d + idx) = o;
}

// Row t of S'[t,s]: mask by index (s<=t), max, sum-exp, write P bf16. One row per block.
__global__ __launch_bounds__(256) void col_softmax(const float* __restrict__ S, u16* __restrict__ P)
{
  const int t = blockIdx.x;
  const long long rowOff = ((long long)blockIdx.y * 2048 + t) * 2048;
  const float* row = S + rowOff;
  u16* prow = P + rowOff;
  const int tid = threadIdx.x;
  const int i0 = tid * 4, i1 = 1024 + tid * 4;

  f32x4 a = *(const f32x4*)(row + i0);
  f32x4 b = *(const f32x4*)(row + i1);
  float v[8];
#pragma unroll
  for (int j = 0; j < 4; ++j) {
    v[j]     = (i0 + j <= t) ? a[j] : -1e30f;  // masked/unwritten entries discarded by index
    v[4 + j] = (i1 + j <= t) ? b[j] : -1e30f;
  }
  float m = v[0];
#pragma unroll
  for (int j = 1; j < 8; ++j) m = fmaxf(m, v[j]);
#pragma unroll
  for (int off = 32; off; off >>= 1) m = fmaxf(m, __shfl_xor(m, off));
  __shared__ float red[4];
  __shared__ float red2[4];
  if ((tid & 63) == 0) red[tid >> 6] = m;
  __syncthreads();
  m = fmaxf(fmaxf(red[0], red[1]), fmaxf(red[2], red[3]));

  float e[8]; float ssum = 0.f;
#pragma unroll
  for (int j = 0; j < 8; ++j) { e[j] = __expf(v[j] - m); ssum += e[j]; }
#pragma unroll
  for (int off = 32; off; off >>= 1) ssum += __shfl_xor(ssum, off);
  if ((tid & 63) == 0) red2[tid >> 6] = ssum;
  __syncthreads();
  ssum = red2[0] + red2[1] + red2[2] + red2[3];
  const float inv = 1.0f / ssum;
  u16x4 o0, o1;
#pragma unroll
  for (int j = 0; j < 4; ++j) { o0[j] = f2bf(e[j] * inv); o1[j] = f2bf(e[4 + j] * inv); }
  *(u16x4*)(prow + i0) = o0;
  *(u16x4*)(prow + i1) = o1;
}

extern "C" void kernel_launch(void* const* d_in, const int* in_sizes, int n_in,
                              void* d_out, int out_size, void* d_ws, size_t ws_size,
                              hipStream_t stream)
{
  const float* Q  = (const float*)d_in[0];
  const float* K  = (const float*)d_in[1];
  const float* V  = (const float*)d_in[2];
  const float* WQ = (const float*)d_in[3];
  const float* WK = (const float*)d_in[4];
  const float* WV = (const float*)d_in[5];
  float* out = (float*)d_out;

  const size_t MB = 1ull << 20;
  char* w = (char*)d_ws;
  if (ws_size < 262 * MB) {
    fprintf(stderr, "kernel_launch: workspace too small (%zu B, need >= %zu B)\n",
            ws_size, (size_t)(262 * MB));
    return;
  }

  // ws layout (MB): [0,6) weights bf16 | [6,70) Qd_t | [70,134) Kd_t | [134,198) Vd
  // [198, ...) transient: transposed-input buffer (64MB), later S(fp32)+P(bf16) chunks
  u16* wq    = (u16*)(w + 0 * MB);
  u16* wk    = (u16*)(w + 2 * MB);
  u16* wv    = (u16*)(w + 4 * MB);
  u16* qdt   = (u16*)(w + 6 * MB);
  u16* kdt   = (u16*)(w + 70 * MB);
  u16* vd    = (u16*)(w + 134 * MB);
  u16* trans = (u16*)(w + 198 * MB);
  float* S   = (float*)(w + 198 * MB);

  long long freeMB = (long long)(ws_size / MB) - 198;
  int chunk = (int)(freeMB / 24);  // 16MB S + 8MB P per batch
  if (chunk > 8) chunk = 8;
  u16* P = (u16*)(w + (198 + (size_t)chunk * 16) * MB);

  conv_weights<<<dim3(1024, 3), 256, 0, stream>>>(WQ, WK, WV, wq, wk, wv);

  // Projections. Qd_t/Kd_t stored (b, seq, o); Vd stored (b, o, seq).
  conv_transpose<<<dim3(32, 16, 16), dim3(64, 4), 0, stream>>>(Q, trans);
  gemm_bt<true, false, false><<<dim3(8, 256, 1), 256, 0, stream>>>(
      trans, wq, qdt, 1024, 1024, 1024, 1024, 0, 0, 0, 1.0f);
  conv_transpose<<<dim3(32, 16, 16), dim3(64, 4), 0, stream>>>(K, trans);
  gemm_bt<true, false, false><<<dim3(8, 256, 1), 256, 0, stream>>>(
      trans, wk, kdt, 1024, 1024, 1024, 1024, 0, 0, 0, 1.0f);
  conv_transpose<<<dim3(32, 16, 16), dim3(64, 4), 0, stream>>>(V, trans);
  gemm_bt<true, false, false><<<dim3(16, 8, 16), 256, 0, stream>>>(
      wv, trans, vd, 1024, 1024, 1024, 2048,
      0, (long long)2048 * 1024, (long long)1024 * 2048, 1.0f);

  // Attention per batch-chunk: S'[t,s] = Kd_t[t,:]·Qd_t[s,:]/32 (skip s>t tiles),
  // row-softmax over s (masked by index), out[o,t] = sum_s Vd[o,s] P[t,s].
  for (int b0 = 0; b0 < 16; b0 += chunk) {
    const int nb = (16 - b0) < chunk ? (16 - b0) : chunk;
    gemm_bt<false, true, false><<<dim3(16, 16, nb), 256, 0, stream>>>(
        kdt + (long long)b0 * 2048 * 1024, qdt + (long long)b0 * 2048 * 1024, S,
        1024, 1024, 1024, 2048,
        (long long)2048 * 1024, (long long)2048 * 1024, (long long)2048 * 2048, 0.03125f);
    col_softmax<<<dim3(2048, nb), 256, 0, stream>>>(S, P);
    gemm_bt<false, false, true><<<dim3(16, 8, nb), 256, 0, stream>>>(
        vd + (long long)b0 * 1024 * 2048, P, out + (long long)b0 * 1024 * 2048,
        2048, 2048, 2048, 2048,
        (long long)1024 * 2048, (long long)2048 * 2048, (long long)1024 * 2048, 1.0f);
  }
}

// Round 3
// 874.541 us; speedup vs baseline: 1.1043x; 1.1043x over previous
//
#include <hip/hip_runtime.h>
#include <cstdio>

typedef unsigned short u16;
typedef float f32x4 __attribute__((ext_vector_type(4)));
typedef __bf16 bf16x8 __attribute__((ext_vector_type(8)));
typedef u16 u16x8 __attribute__((ext_vector_type(8)));
typedef u16 u16x4 __attribute__((ext_vector_type(4)));

__device__ __forceinline__ u16 f2bf(float x) {
  unsigned u = __float_as_uint(x);
  u = (u + 0x7FFFu + ((u >> 16) & 1u)) >> 16;
  return (u16)u;
}

__device__ __forceinline__ f32x4 mfma_bf16(bf16x8 a, bf16x8 b, f32x4 c) {
  return __builtin_amdgcn_mfma_f32_16x16x32_bf16(a, b, c, 0, 0, 0);
}

// async global->LDS, 16B per lane. LDS dest = wave-uniform base + lane*16.
__device__ __forceinline__ void gload_lds16(const void* g, void* l) {
  __builtin_amdgcn_global_load_lds(
      (const __attribute__((address_space(1))) void*)g,
      (__attribute__((address_space(3))) void*)l, 16, 0, 0);
}

// C[m,n] = scale * sum_k A[m,k] * B[n,k]   (both operands K-contiguous)
// 256x256 tile, BK=64, 512 threads (8 waves, 2M x 4N), per-wave 128x64 output.
// 2-phase double-buffered pipeline (T3-minimum): STAGE(next) -> compute(cur) ->
// syncthreads (vmcnt(0)+barrier) -> flip. Loads issue before compute so HBM
// latency hides under the 64 MFMA/wave of the current tile.
template <bool BF16OUT, bool SKIP_UPPER, bool KLIMIT>
__global__ __launch_bounds__(512, 2) void gemm_bt(
    const u16* __restrict__ A, const u16* __restrict__ B, void* __restrict__ Cv,
    int K, int lda, int ldb, int ldc,
    long long sAz, long long sBz, long long sCz, float scale)
{
  const int n0 = blockIdx.x * 256;
  const int m0 = blockIdx.y * 256;
  if (SKIP_UPPER && n0 > m0 + 255) return;  // fully-masked score tile (s > t everywhere)
  const int z = blockIdx.z;
  A += (long long)z * sAz;
  B += (long long)z * sBz;

  const int tid = threadIdx.x;
  const int wave = tid >> 6, lane = tid & 63;
  const int wr = wave >> 2, wc = wave & 3;  // 2 x 4 wave grid

  __shared__ u16 lA[2][256 * 64];  // 2 x 32KB
  __shared__ u16 lB[2][256 * 64];  // 2 x 32KB  (total 128KB)

  f32x4 acc[8][4] = {};

  int kEnd = K;
  if (KLIMIT) { int ke = n0 + 256; kEnd = ke < K ? ke : K; }  // P[t,s]==0 for s>t
  const int nt = kEnd >> 6;

  // staging: 512 lanes x 16B = 64 rows (of 64 u16) per call; 4 calls per operand.
  // wave w covers rows i*64 + w*8 .. +8 (lane>>3), cols (lane&7)*8 .. +8
  const int srow = wave * 8 + (lane >> 3);
  const int scol = (lane & 7) * 8;
  const u16* gA = A + (long long)(m0 + srow) * lda + scol;
  const u16* gB = B + (long long)(n0 + srow) * ldb + scol;
  const int wbase = wave * 512;  // wave-uniform LDS elem offset within a 64-row group

  const int frow = lane & 15, fk = (lane >> 4) * 8;

  // prologue: stage tile 0 into buf 0
#pragma unroll
  for (int i = 0; i < 4; ++i) {
    gload_lds16(gA + (long long)i * 64 * lda, &lA[0][i * 4096 + wbase]);
    gload_lds16(gB + (long long)i * 64 * ldb, &lB[0][i * 4096 + wbase]);
  }
  __syncthreads();  // vmcnt(0) + barrier: tile 0 ready

  int cur = 0;
  for (int t = 0; t < nt; ++t) {
    if (t + 1 < nt) {
      const long long k0 = (long long)(t + 1) * 64;
#pragma unroll
      for (int i = 0; i < 4; ++i) {
        gload_lds16(gA + (long long)i * 64 * lda + k0, &lA[cur ^ 1][i * 4096 + wbase]);
        gload_lds16(gB + (long long)i * 64 * ldb + k0, &lB[cur ^ 1][i * 4096 + wbase]);
      }
    }
#pragma unroll
    for (int kk = 0; kk < 64; kk += 32) {
      bf16x8 af[8], bfr[4];
#pragma unroll
      for (int m = 0; m < 8; ++m)
        af[m] = *(const bf16x8*)(&lA[cur][(wr * 128 + m * 16 + frow) * 64 + kk + fk]);
#pragma unroll
      for (int n = 0; n < 4; ++n)
        bfr[n] = *(const bf16x8*)(&lB[cur][(wc * 64 + n * 16 + frow) * 64 + kk + fk]);
#pragma unroll
      for (int m = 0; m < 8; ++m)
#pragma unroll
        for (int n = 0; n < 4; ++n)
          acc[m][n] = mfma_bf16(af[m], bfr[n], acc[m][n]);
    }
    __syncthreads();  // drains prefetch (vmcnt 0) + all waves done reading cur
    cur ^= 1;
  }

  // C/D layout: col = lane&15, row = (lane>>4)*4 + r  [m89-verified]
  const int crow0 = m0 + wr * 128 + (lane >> 4) * 4;
  const int ccol0 = n0 + wc * 64 + (lane & 15);
  if (BF16OUT) {
    u16* C = (u16*)Cv + (long long)z * sCz;
#pragma unroll
    for (int m = 0; m < 8; ++m)
#pragma unroll
      for (int n = 0; n < 4; ++n)
#pragma unroll
        for (int r = 0; r < 4; ++r)
          C[(long long)(crow0 + m * 16 + r) * ldc + ccol0 + n * 16] = f2bf(acc[m][n][r] * scale);
  } else {
    float* C = (float*)Cv + (long long)z * sCz;
#pragma unroll
    for (int m = 0; m < 8; ++m)
#pragma unroll
      for (int n = 0; n < 4; ++n)
#pragma unroll
        for (int r = 0; r < 4; ++r)
          C[(long long)(crow0 + m * 16 + r) * ldc + ccol0 + n * 16] = acc[m][n][r] * scale;
  }
}

// (b, i, s) fp32  ->  (b, s, i) bf16 ; one 64x64 tile per block, block (64,4)
__global__ __launch_bounds__(256) void conv_transpose(const float* __restrict__ src, u16* __restrict__ dst)
{
  const int b = blockIdx.z;
  const float* s = src + (long long)b * 1024 * 2048;
  u16* d = dst + (long long)b * 2048 * 1024;
  const int s0 = blockIdx.x * 64, i0 = blockIdx.y * 64;
  const int tx = threadIdx.x, ty = threadIdx.y;
  __shared__ float tile[64][65];
#pragma unroll
  for (int r = 0; r < 16; ++r)
    tile[r * 4 + ty][tx] = s[(long long)(i0 + r * 4 + ty) * 2048 + s0 + tx];
  __syncthreads();
#pragma unroll
  for (int r = 0; r < 16; ++r)
    d[(long long)(s0 + r * 4 + ty) * 1024 + i0 + tx] = f2bf(tile[tx][r * 4 + ty]);
}

__global__ __launch_bounds__(256) void conv_weights(
    const float* __restrict__ a, const float* __restrict__ b, const float* __restrict__ c,
    u16* __restrict__ oa, u16* __restrict__ ob, u16* __restrict__ oc)
{
  const int which = blockIdx.y;
  const float* s = which == 0 ? a : which == 1 ? b : c;
  u16* d = which == 0 ? oa : which == 1 ? ob : oc;
  const int idx = (blockIdx.x * 256 + threadIdx.x) * 4;
  f32x4 v = *(const f32x4*)(s + idx);
  u16x4 o;
#pragma unroll
  for (int j = 0; j < 4; ++j) o[j] = f2bf(v[j]);
  *(u16x4*)(d + idx) = o;
}

// Row t of S'[t,s]: mask by index (s<=t), max, sum-exp, write P bf16. One row per block.
__global__ __launch_bounds__(256) void col_softmax(const float* __restrict__ S, u16* __restrict__ P)
{
  const int t = blockIdx.x;
  const long long rowOff = ((long long)blockIdx.y * 2048 + t) * 2048;
  const float* row = S + rowOff;
  u16* prow = P + rowOff;
  const int tid = threadIdx.x;
  const int i0 = tid * 4, i1 = 1024 + tid * 4;

  f32x4 a = *(const f32x4*)(row + i0);
  f32x4 b = *(const f32x4*)(row + i1);
  float v[8];
#pragma unroll
  for (int j = 0; j < 4; ++j) {
    v[j]     = (i0 + j <= t) ? a[j] : -1e30f;  // masked/unwritten entries discarded by index
    v[4 + j] = (i1 + j <= t) ? b[j] : -1e30f;
  }
  float m = v[0];
#pragma unroll
  for (int j = 1; j < 8; ++j) m = fmaxf(m, v[j]);
#pragma unroll
  for (int off = 32; off; off >>= 1) m = fmaxf(m, __shfl_xor(m, off));
  __shared__ float red[4];
  __shared__ float red2[4];
  if ((tid & 63) == 0) red[tid >> 6] = m;
  __syncthreads();
  m = fmaxf(fmaxf(red[0], red[1]), fmaxf(red[2], red[3]));

  float e[8]; float ssum = 0.f;
#pragma unroll
  for (int j = 0; j < 8; ++j) { e[j] = __expf(v[j] - m); ssum += e[j]; }
#pragma unroll
  for (int off = 32; off; off >>= 1) ssum += __shfl_xor(ssum, off);
  if ((tid & 63) == 0) red2[tid >> 6] = ssum;
  __syncthreads();
  ssum = red2[0] + red2[1] + red2[2] + red2[3];
  const float inv = 1.0f / ssum;
  u16x4 o0, o1;
#pragma unroll
  for (int j = 0; j < 4; ++j) { o0[j] = f2bf(e[j] * inv); o1[j] = f2bf(e[4 + j] * inv); }
  *(u16x4*)(prow + i0) = o0;
  *(u16x4*)(prow + i1) = o1;
}

extern "C" void kernel_launch(void* const* d_in, const int* in_sizes, int n_in,
                              void* d_out, int out_size, void* d_ws, size_t ws_size,
                              hipStream_t stream)
{
  const float* Q  = (const float*)d_in[0];
  const float* K  = (const float*)d_in[1];
  const float* V  = (const float*)d_in[2];
  const float* WQ = (const float*)d_in[3];
  const float* WK = (const float*)d_in[4];
  const float* WV = (const float*)d_in[5];
  float* out = (float*)d_out;

  const size_t MB = 1ull << 20;
  char* w = (char*)d_ws;
  if (ws_size < 262 * MB) {
    fprintf(stderr, "kernel_launch: workspace too small (%zu B, need >= %zu B)\n",
            ws_size, (size_t)(262 * MB));
    return;
  }

  // ws layout (MB): [0,6) weights bf16 | [6,70) Qd_t | [70,134) Kd_t | [134,198) Vd
  // [198, ...) transient: transposed-input buffer (64MB), later S(fp32)+P(bf16) chunks
  u16* wq    = (u16*)(w + 0 * MB);
  u16* wk    = (u16*)(w + 2 * MB);
  u16* wv    = (u16*)(w + 4 * MB);
  u16* qdt   = (u16*)(w + 6 * MB);
  u16* kdt   = (u16*)(w + 70 * MB);
  u16* vd    = (u16*)(w + 134 * MB);
  u16* trans = (u16*)(w + 198 * MB);
  float* S   = (float*)(w + 198 * MB);

  long long freeMB = (long long)(ws_size / MB) - 198;
  int chunk = (int)(freeMB / 24);  // 16MB S + 8MB P per batch
  if (chunk > 8) chunk = 8;
  u16* P = (u16*)(w + (198 + (size_t)chunk * 16) * MB);

  conv_weights<<<dim3(1024, 3), 256, 0, stream>>>(WQ, WK, WV, wq, wk, wv);

  // Projections. Qd_t/Kd_t stored (b, seq, o) = one (32768 x 1024) GEMM each;
  // Vd stored (b, o, seq), per-batch z.
  conv_transpose<<<dim3(32, 16, 16), dim3(64, 4), 0, stream>>>(Q, trans);
  gemm_bt<true, false, false><<<dim3(4, 128, 1), 512, 0, stream>>>(
      trans, wq, qdt, 1024, 1024, 1024, 1024, 0, 0, 0, 1.0f);
  conv_transpose<<<dim3(32, 16, 16), dim3(64, 4), 0, stream>>>(K, trans);
  gemm_bt<true, false, false><<<dim3(4, 128, 1), 512, 0, stream>>>(
      trans, wk, kdt, 1024, 1024, 1024, 1024, 0, 0, 0, 1.0f);
  conv_transpose<<<dim3(32, 16, 16), dim3(64, 4), 0, stream>>>(V, trans);
  gemm_bt<true, false, false><<<dim3(8, 4, 16), 512, 0, stream>>>(
      wv, trans, vd, 1024, 1024, 1024, 2048,
      0, (long long)2048 * 1024, (long long)1024 * 2048, 1.0f);

  // Attention per batch-chunk: S'[t,s] = Kd_t[t,:]·Qd_t[s,:]/32 (skip s>t tiles),
  // row-softmax over s (masked by index), out[o,t] = sum_s Vd[o,s] P[t,s].
  for (int b0 = 0; b0 < 16; b0 += chunk) {
    const int nb = (16 - b0) < chunk ? (16 - b0) : chunk;
    gemm_bt<false, true, false><<<dim3(8, 8, nb), 512, 0, stream>>>(
        kdt + (long long)b0 * 2048 * 1024, qdt + (long long)b0 * 2048 * 1024, S,
        1024, 1024, 1024, 2048,
        (long long)2048 * 1024, (long long)2048 * 1024, (long long)2048 * 2048, 0.03125f);
    col_softmax<<<dim3(2048, nb), 256, 0, stream>>>(S, P);
    gemm_bt<false, false, true><<<dim3(8, 4, nb), 512, 0, stream>>>(
        vd + (long long)b0 * 1024 * 2048, P, out + (long long)b0 * 1024 * 2048,
        2048, 2048, 2048, 2048,
        (long long)1024 * 2048, (long long)2048 * 2048, (long long)1024 * 2048, 1.0f);
  }
}

// Round 4
// 767.912 us; speedup vs baseline: 1.2576x; 1.1389x over previous
//
#include <hip/hip_runtime.h>
#include <cstdio>

typedef unsigned short u16;
typedef float f32x4 __attribute__((ext_vector_type(4)));
typedef __bf16 bf16x8 __attribute__((ext_vector_type(8)));
typedef u16 u16x4 __attribute__((ext_vector_type(4)));

__device__ __forceinline__ u16 f2bf(float x) {
  unsigned u = __float_as_uint(x);
  u = (u + 0x7FFFu + ((u >> 16) & 1u)) >> 16;
  return (u16)u;
}

__device__ __forceinline__ f32x4 mfma_bf16(bf16x8 a, bf16x8 b, f32x4 c) {
  return __builtin_amdgcn_mfma_f32_16x16x32_bf16(a, b, c, 0, 0, 0);
}

// async global->LDS, 16B per lane. LDS dest = wave-uniform base + lane*16.
__device__ __forceinline__ void gload_lds16(const void* g, void* l) {
  __builtin_amdgcn_global_load_lds(
      (const __attribute__((address_space(1))) void*)g,
      (__attribute__((address_space(3))) void*)l, 16, 0, 0);
}

// C[m,n] = scale * sum_k A[m,k] * B[n,k]   (both operands K-contiguous)
// BM=256 x BN=128, BK=64. 512 threads = 8 waves (4M x 2N), per-wave 64x64 out.
// TRIPLE-buffered LDS (48KB/buf): tile t reads buf[t%3]; tile t+2 staged into
// buf[(t+2)%3] during tile t (that buffer's last reader was tile t-1, already
// past its phase barrier -> race-free). Counted vmcnt(6) at tile boundary
// keeps t+2's 6 loads/wave in flight across barriers (T4); never drains to 0
// mid-loop. LDS 16B-slot XOR-swizzle (slot ^= row&7) applied via pre-swizzled
// global source (linear gload_lds dest) + swizzled ds_read address (T2).
// Requires nt >= 2 (K >= 128) and M%256==0, N%128==0, K%64==0.
template <bool BF16OUT, bool SKIP_UPPER, bool KLIMIT>
__global__ __launch_bounds__(512, 2) void gemm_bt(
    const u16* __restrict__ A, const u16* __restrict__ B, void* __restrict__ Cv,
    int K, int lda, int ldb, int ldc,
    long long sAz, long long sBz, long long sCz, float scale)
{
  const int n0 = blockIdx.x * 128;
  const int m0 = blockIdx.y * 256;
  if (SKIP_UPPER && n0 > m0 + 255) return;  // fully-masked score tile (s > t everywhere)
  const int z = blockIdx.z;
  A += (long long)z * sAz;
  B += (long long)z * sBz;

  const int tid = threadIdx.x;
  const int wave = tid >> 6, lane = tid & 63;
  const int wr = wave >> 1, wc = wave & 1;  // 4M x 2N wave grid

  // per buffer: A [256][64] u16 at 0, B [128][64] u16 at 16384; 24576 u16 = 48KB
  __shared__ u16 lds[3][24576];

  f32x4 acc[4][4] = {};

  int kEnd = K;
  if (KLIMIT) { int ke = n0 + 128; kEnd = ke < K ? ke : K; }  // P[t,s]==0 for s>t
  const int nt = kEnd >> 6;  // always >= 2 for our launches

  // ---- staging geometry: chunk c covers rows c*8..c*8+7; lane -> row c*8+(lane>>3),
  // phys 16B slot lane&7. Pre-swizzle SOURCE so LDS stays linear:
  // logical slot = phys ^ (row&7); (c*8)&7==0 so row&7 == (lane>>3)&7.
  const int sOff = ((lane & 7) ^ ((lane >> 3) & 7)) * 8;  // element offset
  const u16* gAs = A + (long long)(m0 + (lane >> 3)) * lda + sOff;
  const u16* gBs = B + (long long)(n0 + (lane >> 3)) * ldb + sOff;

  // ---- read geometry: logical (row r, slot s) lives at phys slot s^(r&7).
  // af rows: wr*64 + m*16 + frow; bfr rows: wc*64 + n*16 + frow; (r&7)==frow&7.
  const int frow = lane & 15, g = lane >> 4, swz = frow & 7;
  const int aoff0 = (wr * 64 + frow) * 64 + ((g    ) ^ swz) * 8;   // kk=0
  const int aoff1 = (wr * 64 + frow) * 64 + ((4 + g) ^ swz) * 8;   // kk=32
  const int boff0 = 16384 + (wc * 64 + frow) * 64 + ((g    ) ^ swz) * 8;
  const int boff1 = 16384 + (wc * 64 + frow) * 64 + ((4 + g) ^ swz) * 8;

#define STAGE_A(T, BUF)                                                        \
  {                                                                            \
    const long long kc = (long long)(T) * 64;                                  \
    _Pragma("unroll")                                                          \
    for (int j = 0; j < 4; ++j) {                                              \
      const int c = j * 8 + wave;                                              \
      gload_lds16(gAs + (long long)(c * 8) * lda + kc, &lds[BUF][c * 512]);    \
    }                                                                          \
  }
#define STAGE_B(T, BUF)                                                        \
  {                                                                            \
    const long long kc = (long long)(T) * 64;                                  \
    _Pragma("unroll")                                                          \
    for (int j = 0; j < 2; ++j) {                                              \
      const int c = j * 8 + wave;                                              \
      gload_lds16(gBs + (long long)(c * 8) * ldb + kc,                         \
                  &lds[BUF][16384 + c * 512]);                                 \
    }                                                                          \
  }

  // ---- prologue: stage t0 -> buf0, t1 -> buf1; wait t0 (6 newest = t1 stay in flight)
  STAGE_A(0, 0) STAGE_B(0, 0)
  if (nt > 1) {
    STAGE_A(1, 1) STAGE_B(1, 1)
    asm volatile("s_waitcnt vmcnt(6)" ::: "memory");
  } else {
    asm volatile("s_waitcnt vmcnt(0)" ::: "memory");
  }
  __builtin_amdgcn_s_barrier();

  int cur = 0, nxt = 2;
  for (int t = 0; t < nt; ++t) {
    const u16* bb = &lds[cur][0];
    const bool pf = (t + 2 < nt);
    bf16x8 A0[4], A1[4], B0k0[2], B0k1[2], B1k0[2], B1k1[2];

    // ---- phase 1: ds-read A frags (8) + B n0-1 (4); stage A(t+2); MFMA n0-1
#pragma unroll
    for (int m = 0; m < 4; ++m) {
      A0[m] = *(const bf16x8*)(bb + aoff0 + m * 1024);
      A1[m] = *(const bf16x8*)(bb + aoff1 + m * 1024);
    }
#pragma unroll
    for (int n = 0; n < 2; ++n) {
      B0k0[n] = *(const bf16x8*)(bb + boff0 + n * 1024);
      B0k1[n] = *(const bf16x8*)(bb + boff1 + n * 1024);
    }
    if (pf) STAGE_A(t + 2, nxt)
    __builtin_amdgcn_s_barrier();
    __builtin_amdgcn_s_setprio(1);
#pragma unroll
    for (int m = 0; m < 4; ++m)
#pragma unroll
      for (int n = 0; n < 2; ++n)
        acc[m][n] = mfma_bf16(A0[m], B0k0[n], acc[m][n]);
#pragma unroll
    for (int m = 0; m < 4; ++m)
#pragma unroll
      for (int n = 0; n < 2; ++n)
        acc[m][n] = mfma_bf16(A1[m], B0k1[n], acc[m][n]);
    __builtin_amdgcn_s_setprio(0);
    __builtin_amdgcn_s_barrier();

    // ---- phase 2: ds-read B n2-3 (4, A reused); stage B(t+2); MFMA n2-3
#pragma unroll
    for (int n = 0; n < 2; ++n) {
      B1k0[n] = *(const bf16x8*)(bb + boff0 + (2 + n) * 1024);
      B1k1[n] = *(const bf16x8*)(bb + boff1 + (2 + n) * 1024);
    }
    if (pf) STAGE_B(t + 2, nxt)
    __builtin_amdgcn_s_barrier();
    __builtin_amdgcn_s_setprio(1);
#pragma unroll
    for (int m = 0; m < 4; ++m)
#pragma unroll
      for (int n = 0; n < 2; ++n)
        acc[m][n + 2] = mfma_bf16(A0[m], B1k0[n], acc[m][n + 2]);
#pragma unroll
    for (int m = 0; m < 4; ++m)
#pragma unroll
      for (int n = 0; n < 2; ++n)
        acc[m][n + 2] = mfma_bf16(A1[m], B1k1[n], acc[m][n + 2]);
    __builtin_amdgcn_s_setprio(0);
    // ---- tile boundary: retire t+1's 6 loads; keep t+2's 6 in flight
    if (pf) asm volatile("s_waitcnt vmcnt(6)" ::: "memory");
    else    asm volatile("s_waitcnt vmcnt(0)" ::: "memory");
    __builtin_amdgcn_s_barrier();
    cur = (cur == 2) ? 0 : cur + 1;
    nxt = (nxt == 2) ? 0 : nxt + 1;
  }
#undef STAGE_A
#undef STAGE_B

  // C/D layout: col = lane&15, row = (lane>>4)*4 + r  [m89-verified]
  const int crow0 = m0 + wr * 64 + (lane >> 4) * 4;
  const int ccol0 = n0 + wc * 64 + (lane & 15);
  if (BF16OUT) {
    u16* C = (u16*)Cv + (long long)z * sCz;
#pragma unroll
    for (int m = 0; m < 4; ++m)
#pragma unroll
      for (int n = 0; n < 4; ++n)
#pragma unroll
        for (int r = 0; r < 4; ++r)
          C[(long long)(crow0 + m * 16 + r) * ldc + ccol0 + n * 16] = f2bf(acc[m][n][r] * scale);
  } else {
    float* C = (float*)Cv + (long long)z * sCz;
#pragma unroll
    for (int m = 0; m < 4; ++m)
#pragma unroll
      for (int n = 0; n < 4; ++n)
#pragma unroll
        for (int r = 0; r < 4; ++r)
          C[(long long)(crow0 + m * 16 + r) * ldc + ccol0 + n * 16] = acc[m][n][r] * scale;
  }
}

// (b, i, s) fp32  ->  (b, s, i) bf16 ; one 64x64 tile per block, block (64,4)
__global__ __launch_bounds__(256) void conv_transpose(const float* __restrict__ src, u16* __restrict__ dst)
{
  const int b = blockIdx.z;
  const float* s = src + (long long)b * 1024 * 2048;
  u16* d = dst + (long long)b * 2048 * 1024;
  const int s0 = blockIdx.x * 64, i0 = blockIdx.y * 64;
  const int tx = threadIdx.x, ty = threadIdx.y;
  __shared__ float tile[64][65];
#pragma unroll
  for (int r = 0; r < 16; ++r)
    tile[r * 4 + ty][tx] = s[(long long)(i0 + r * 4 + ty) * 2048 + s0 + tx];
  __syncthreads();
#pragma unroll
  for (int r = 0; r < 16; ++r)
    d[(long long)(s0 + r * 4 + ty) * 1024 + i0 + tx] = f2bf(tile[tx][r * 4 + ty]);
}

__global__ __launch_bounds__(256) void conv_weights(
    const float* __restrict__ a, const float* __restrict__ b, const float* __restrict__ c,
    u16* __restrict__ oa, u16* __restrict__ ob, u16* __restrict__ oc)
{
  const int which = blockIdx.y;
  const float* s = which == 0 ? a : which == 1 ? b : c;
  u16* d = which == 0 ? oa : which == 1 ? ob : oc;
  const int idx = (blockIdx.x * 256 + threadIdx.x) * 4;
  f32x4 v = *(const f32x4*)(s + idx);
  u16x4 o;
#pragma unroll
  for (int j = 0; j < 4; ++j) o[j] = f2bf(v[j]);
  *(u16x4*)(d + idx) = o;
}

// Row t of S'[t,s]: mask by index (s<=t), max, sum-exp, write P bf16. One row per block.
__global__ __launch_bounds__(256) void col_softmax(const float* __restrict__ S, u16* __restrict__ P)
{
  const int t = blockIdx.x;
  const long long rowOff = ((long long)blockIdx.y * 2048 + t) * 2048;
  const float* row = S + rowOff;
  u16* prow = P + rowOff;
  const int tid = threadIdx.x;
  const int i0 = tid * 4, i1 = 1024 + tid * 4;

  f32x4 a = *(const f32x4*)(row + i0);
  f32x4 b = *(const f32x4*)(row + i1);
  float v[8];
#pragma unroll
  for (int j = 0; j < 4; ++j) {
    v[j]     = (i0 + j <= t) ? a[j] : -1e30f;  // masked/unwritten entries discarded by index
    v[4 + j] = (i1 + j <= t) ? b[j] : -1e30f;
  }
  float m = v[0];
#pragma unroll
  for (int j = 1; j < 8; ++j) m = fmaxf(m, v[j]);
#pragma unroll
  for (int off = 32; off; off >>= 1) m = fmaxf(m, __shfl_xor(m, off));
  __shared__ float red[4];
  __shared__ float red2[4];
  if ((tid & 63) == 0) red[tid >> 6] = m;
  __syncthreads();
  m = fmaxf(fmaxf(red[0], red[1]), fmaxf(red[2], red[3]));

  float e[8]; float ssum = 0.f;
#pragma unroll
  for (int j = 0; j < 8; ++j) { e[j] = __expf(v[j] - m); ssum += e[j]; }
#pragma unroll
  for (int off = 32; off; off >>= 1) ssum += __shfl_xor(ssum, off);
  if ((tid & 63) == 0) red2[tid >> 6] = ssum;
  __syncthreads();
  ssum = red2[0] + red2[1] + red2[2] + red2[3];
  const float inv = 1.0f / ssum;
  u16x4 o0, o1;
#pragma unroll
  for (int j = 0; j < 4; ++j) { o0[j] = f2bf(e[j] * inv); o1[j] = f2bf(e[4 + j] * inv); }
  *(u16x4*)(prow + i0) = o0;
  *(u16x4*)(prow + i1) = o1;
}

extern "C" void kernel_launch(void* const* d_in, const int* in_sizes, int n_in,
                              void* d_out, int out_size, void* d_ws, size_t ws_size,
                              hipStream_t stream)
{
  const float* Q  = (const float*)d_in[0];
  const float* K  = (const float*)d_in[1];
  const float* V  = (const float*)d_in[2];
  const float* WQ = (const float*)d_in[3];
  const float* WK = (const float*)d_in[4];
  const float* WV = (const float*)d_in[5];
  float* out = (float*)d_out;

  const size_t MB = 1ull << 20;
  char* w = (char*)d_ws;
  if (ws_size < 262 * MB) {
    fprintf(stderr, "kernel_launch: workspace too small (%zu B, need >= %zu B)\n",
            ws_size, (size_t)(262 * MB));
    return;
  }

  // ws layout (MB): [0,6) weights bf16 | [6,70) Qd_t | [70,134) Kd_t | [134,198) Vd
  // [198, ...) transient: transposed-input buffer (64MB), later S(fp32)+P(bf16) chunks
  u16* wq    = (u16*)(w + 0 * MB);
  u16* wk    = (u16*)(w + 2 * MB);
  u16* wv    = (u16*)(w + 4 * MB);
  u16* qdt   = (u16*)(w + 6 * MB);
  u16* kdt   = (u16*)(w + 70 * MB);
  u16* vd    = (u16*)(w + 134 * MB);
  u16* trans = (u16*)(w + 198 * MB);
  float* S   = (float*)(w + 198 * MB);

  long long freeMB = (long long)(ws_size / MB) - 198;
  int chunk = (int)(freeMB / 24);  // 16MB S + 8MB P per batch
  if (chunk > 8) chunk = 8;
  u16* P = (u16*)(w + (198 + (size_t)chunk * 16) * MB);

  conv_weights<<<dim3(1024, 3), 256, 0, stream>>>(WQ, WK, WV, wq, wk, wv);

  // Projections. Qd_t/Kd_t stored (b, seq, o) = one (32768 x 1024) GEMM each;
  // Vd stored (b, o, seq), per-batch z.
  conv_transpose<<<dim3(32, 16, 16), dim3(64, 4), 0, stream>>>(Q, trans);
  gemm_bt<true, false, false><<<dim3(8, 128, 1), 512, 0, stream>>>(
      trans, wq, qdt, 1024, 1024, 1024, 1024, 0, 0, 0, 1.0f);
  conv_transpose<<<dim3(32, 16, 16), dim3(64, 4), 0, stream>>>(K, trans);
  gemm_bt<true, false, false><<<dim3(8, 128, 1), 512, 0, stream>>>(
      trans, wk, kdt, 1024, 1024, 1024, 1024, 0, 0, 0, 1.0f);
  conv_transpose<<<dim3(32, 16, 16), dim3(64, 4), 0, stream>>>(V, trans);
  gemm_bt<true, false, false><<<dim3(16, 4, 16), 512, 0, stream>>>(
      wv, trans, vd, 1024, 1024, 1024, 2048,
      0, (long long)2048 * 1024, (long long)1024 * 2048, 1.0f);

  // Attention per batch-chunk: S'[t,s] = Kd_t[t,:]·Qd_t[s,:]/32 (skip s>t tiles),
  // row-softmax over s (masked by index), out[o,t] = sum_s Vd[o,s] P[t,s].
  for (int b0 = 0; b0 < 16; b0 += chunk) {
    const int nb = (16 - b0) < chunk ? (16 - b0) : chunk;
    gemm_bt<false, true, false><<<dim3(16, 8, nb), 512, 0, stream>>>(
        kdt + (long long)b0 * 2048 * 1024, qdt + (long long)b0 * 2048 * 1024, S,
        1024, 1024, 1024, 2048,
        (long long)2048 * 1024, (long long)2048 * 1024, (long long)2048 * 2048, 0.03125f);
    col_softmax<<<dim3(2048, nb), 256, 0, stream>>>(S, P);
    gemm_bt<false, false, true><<<dim3(16, 4, nb), 512, 0, stream>>>(
        vd + (long long)b0 * 1024 * 2048, P, out + (long long)b0 * 1024 * 2048,
        2048, 2048, 2048, 2048,
        (long long)1024 * 2048, (long long)2048 * 2048, (long long)1024 * 2048, 1.0f);
  }
}

// Round 5
// 744.849 us; speedup vs baseline: 1.2966x; 1.0310x over previous
//
#include <hip/hip_runtime.h>
#include <cstdio>

typedef unsigned short u16;
typedef float f32x4 __attribute__((ext_vector_type(4)));
typedef __bf16 bf16x8 __attribute__((ext_vector_type(8)));
typedef u16 u16x4 __attribute__((ext_vector_type(4)));

__device__ __forceinline__ u16 f2bf(float x) {
  unsigned u = __float_as_uint(x);
  u = (u + 0x7FFFu + ((u >> 16) & 1u)) >> 16;
  return (u16)u;
}

__device__ __forceinline__ f32x4 mfma_bf16(bf16x8 a, bf16x8 b, f32x4 c) {
  return __builtin_amdgcn_mfma_f32_16x16x32_bf16(a, b, c, 0, 0, 0);
}

// async global->LDS, 16B per lane. LDS dest = wave-uniform base + lane*16.
__device__ __forceinline__ void gload_lds16(const void* g, void* l) {
  __builtin_amdgcn_global_load_lds(
      (const __attribute__((address_space(1))) void*)g,
      (__attribute__((address_space(3))) void*)l, 16, 0, 0);
}

// C[m,n] = scale * sum_k A[m,k] * B[n,k]   (both operands K-contiguous)
// BM=256 x BN=128, BK=64. 512 threads = 8 waves (4M x 2N), per-wave 64x64 out.
// TRIPLE-buffered LDS (48KB/buf), counted vmcnt(6) at tile boundaries (T4),
// 16B-slot XOR swizzle via pre-swizzled global source (T2, conflicts==0).
// NEW (T1): XCD-aware block swizzle within each z-slice. HW round-robins
// consecutive linear blocks across 8 XCDs; remap f -> (f&7)*(nwg/8)+(f>>3)
// so each XCD processes a CONTIGUOUS logical chunk (shared A-panels + B stay
// in that XCD's L2). Requires nwg%8==0 (all our grids) and gx power of 2.
template <bool BF16OUT, bool SKIP_UPPER, bool KLIMIT>
__global__ __launch_bounds__(512, 2) void gemm_bt(
    const u16* __restrict__ A, const u16* __restrict__ B, void* __restrict__ Cv,
    int K, int lda, int ldb, int ldc,
    long long sAz, long long sBz, long long sCz, float scale)
{
  // ---- T1 XCD swizzle (bijective since gridDim.x*gridDim.y % 8 == 0)
  const int gx = gridDim.x;
  const int nwg = gx * gridDim.y;
  const int f0 = blockIdx.x + gx * blockIdx.y;
  const int f = (f0 & 7) * (nwg >> 3) + (f0 >> 3);
  const int bx = f & (gx - 1);
  const int by = f / gx;

  const int n0 = bx * 128;
  const int m0 = by * 256;
  if (SKIP_UPPER && n0 > m0 + 255) return;  // fully-masked score tile (s > t everywhere)
  const int z = blockIdx.z;
  A += (long long)z * sAz;
  B += (long long)z * sBz;

  const int tid = threadIdx.x;
  const int wave = tid >> 6, lane = tid & 63;
  const int wr = wave >> 1, wc = wave & 1;  // 4M x 2N wave grid

  // per buffer: A [256][64] u16 at 0, B [128][64] u16 at 16384; 24576 u16 = 48KB
  __shared__ u16 lds[3][24576];

  f32x4 acc[4][4] = {};

  int kEnd = K;
  if (KLIMIT) { int ke = n0 + 128; kEnd = ke < K ? ke : K; }  // P[t,s]==0 for s>t
  const int nt = kEnd >> 6;  // always >= 2 for our launches

  // ---- staging geometry: chunk c covers rows c*8..c*8+7; lane -> row c*8+(lane>>3),
  // phys 16B slot lane&7. Pre-swizzle SOURCE so LDS stays linear:
  // logical slot = phys ^ (row&7); (c*8)&7==0 so row&7 == (lane>>3)&7.
  const int sOff = ((lane & 7) ^ ((lane >> 3) & 7)) * 8;  // element offset
  const u16* gAs = A + (long long)(m0 + (lane >> 3)) * lda + sOff;
  const u16* gBs = B + (long long)(n0 + (lane >> 3)) * ldb + sOff;

  // ---- read geometry: logical (row r, slot s) lives at phys slot s^(r&7).
  const int frow = lane & 15, g = lane >> 4, swz = frow & 7;
  const int aoff0 = (wr * 64 + frow) * 64 + ((g    ) ^ swz) * 8;   // kk=0
  const int aoff1 = (wr * 64 + frow) * 64 + ((4 + g) ^ swz) * 8;   // kk=32
  const int boff0 = 16384 + (wc * 64 + frow) * 64 + ((g    ) ^ swz) * 8;
  const int boff1 = 16384 + (wc * 64 + frow) * 64 + ((4 + g) ^ swz) * 8;

#define STAGE_A(T, BUF)                                                        \
  {                                                                            \
    const long long kc = (long long)(T) * 64;                                  \
    _Pragma("unroll")                                                          \
    for (int j = 0; j < 4; ++j) {                                              \
      const int c = j * 8 + wave;                                              \
      gload_lds16(gAs + (long long)(c * 8) * lda + kc, &lds[BUF][c * 512]);    \
    }                                                                          \
  }
#define STAGE_B(T, BUF)                                                        \
  {                                                                            \
    const long long kc = (long long)(T) * 64;                                  \
    _Pragma("unroll")                                                          \
    for (int j = 0; j < 2; ++j) {                                              \
      const int c = j * 8 + wave;                                              \
      gload_lds16(gBs + (long long)(c * 8) * ldb + kc,                         \
                  &lds[BUF][16384 + c * 512]);                                 \
    }                                                                          \
  }

  // ---- prologue: stage t0 -> buf0, t1 -> buf1; wait t0 (6 newest = t1 stay in flight)
  STAGE_A(0, 0) STAGE_B(0, 0)
  if (nt > 1) {
    STAGE_A(1, 1) STAGE_B(1, 1)
    asm volatile("s_waitcnt vmcnt(6)" ::: "memory");
  } else {
    asm volatile("s_waitcnt vmcnt(0)" ::: "memory");
  }
  __builtin_amdgcn_s_barrier();

  int cur = 0, nxt = 2;
  for (int t = 0; t < nt; ++t) {
    const u16* bb = &lds[cur][0];
    const bool pf = (t + 2 < nt);
    bf16x8 A0[4], A1[4], B0k0[2], B0k1[2], B1k0[2], B1k1[2];

    // ---- phase 1: ds-read A frags (8) + B n0-1 (4); stage A(t+2); MFMA n0-1
#pragma unroll
    for (int m = 0; m < 4; ++m) {
      A0[m] = *(const bf16x8*)(bb + aoff0 + m * 1024);
      A1[m] = *(const bf16x8*)(bb + aoff1 + m * 1024);
    }
#pragma unroll
    for (int n = 0; n < 2; ++n) {
      B0k0[n] = *(const bf16x8*)(bb + boff0 + n * 1024);
      B0k1[n] = *(const bf16x8*)(bb + boff1 + n * 1024);
    }
    if (pf) STAGE_A(t + 2, nxt)
    __builtin_amdgcn_s_barrier();
    __builtin_amdgcn_s_setprio(1);
#pragma unroll
    for (int m = 0; m < 4; ++m)
#pragma unroll
      for (int n = 0; n < 2; ++n)
        acc[m][n] = mfma_bf16(A0[m], B0k0[n], acc[m][n]);
#pragma unroll
    for (int m = 0; m < 4; ++m)
#pragma unroll
      for (int n = 0; n < 2; ++n)
        acc[m][n] = mfma_bf16(A1[m], B0k1[n], acc[m][n]);
    __builtin_amdgcn_s_setprio(0);
    __builtin_amdgcn_s_barrier();

    // ---- phase 2: ds-read B n2-3 (4, A reused); stage B(t+2); MFMA n2-3
#pragma unroll
    for (int n = 0; n < 2; ++n) {
      B1k0[n] = *(const bf16x8*)(bb + boff0 + (2 + n) * 1024);
      B1k1[n] = *(const bf16x8*)(bb + boff1 + (2 + n) * 1024);
    }
    if (pf) STAGE_B(t + 2, nxt)
    __builtin_amdgcn_s_barrier();
    __builtin_amdgcn_s_setprio(1);
#pragma unroll
    for (int m = 0; m < 4; ++m)
#pragma unroll
      for (int n = 0; n < 2; ++n)
        acc[m][n + 2] = mfma_bf16(A0[m], B1k0[n], acc[m][n + 2]);
#pragma unroll
    for (int m = 0; m < 4; ++m)
#pragma unroll
      for (int n = 0; n < 2; ++n)
        acc[m][n + 2] = mfma_bf16(A1[m], B1k1[n], acc[m][n + 2]);
    __builtin_amdgcn_s_setprio(0);
    // ---- tile boundary: retire t+1's 6 loads; keep t+2's 6 in flight
    if (pf) asm volatile("s_waitcnt vmcnt(6)" ::: "memory");
    else    asm volatile("s_waitcnt vmcnt(0)" ::: "memory");
    __builtin_amdgcn_s_barrier();
    cur = (cur == 2) ? 0 : cur + 1;
    nxt = (nxt == 2) ? 0 : nxt + 1;
  }
#undef STAGE_A
#undef STAGE_B

  // C/D layout: col = lane&15, row = (lane>>4)*4 + r  [m89-verified]
  const int crow0 = m0 + wr * 64 + (lane >> 4) * 4;
  const int ccol0 = n0 + wc * 64 + (lane & 15);
  if (BF16OUT) {
    u16* C = (u16*)Cv + (long long)z * sCz;
#pragma unroll
    for (int m = 0; m < 4; ++m)
#pragma unroll
      for (int n = 0; n < 4; ++n)
#pragma unroll
        for (int r = 0; r < 4; ++r)
          C[(long long)(crow0 + m * 16 + r) * ldc + ccol0 + n * 16] = f2bf(acc[m][n][r] * scale);
  } else {
    float* C = (float*)Cv + (long long)z * sCz;
#pragma unroll
    for (int m = 0; m < 4; ++m)
#pragma unroll
      for (int n = 0; n < 4; ++n)
#pragma unroll
        for (int r = 0; r < 4; ++r)
          C[(long long)(crow0 + m * 16 + r) * ldc + ccol0 + n * 16] = acc[m][n][r] * scale;
  }
}

// (b, i, s) fp32  ->  (b, s, i) bf16 ; one 64x64 tile per block, block (64,4)
__global__ __launch_bounds__(256) void conv_transpose(const float* __restrict__ src, u16* __restrict__ dst)
{
  const int b = blockIdx.z;
  const float* s = src + (long long)b * 1024 * 2048;
  u16* d = dst + (long long)b * 2048 * 1024;
  const int s0 = blockIdx.x * 64, i0 = blockIdx.y * 64;
  const int tx = threadIdx.x, ty = threadIdx.y;
  __shared__ float tile[64][65];
#pragma unroll
  for (int r = 0; r < 16; ++r)
    tile[r * 4 + ty][tx] = s[(long long)(i0 + r * 4 + ty) * 2048 + s0 + tx];
  __syncthreads();
#pragma unroll
  for (int r = 0; r < 16; ++r)
    d[(long long)(s0 + r * 4 + ty) * 1024 + i0 + tx] = f2bf(tile[tx][r * 4 + ty]);
}

__global__ __launch_bounds__(256) void conv_weights(
    const float* __restrict__ a, const float* __restrict__ b, const float* __restrict__ c,
    u16* __restrict__ oa, u16* __restrict__ ob, u16* __restrict__ oc)
{
  const int which = blockIdx.y;
  const float* s = which == 0 ? a : which == 1 ? b : c;
  u16* d = which == 0 ? oa : which == 1 ? ob : oc;
  const int idx = (blockIdx.x * 256 + threadIdx.x) * 4;
  f32x4 v = *(const f32x4*)(s + idx);
  u16x4 o;
#pragma unroll
  for (int j = 0; j < 4; ++j) o[j] = f2bf(v[j]);
  *(u16x4*)(d + idx) = o;
}

// Row t of S'[t,s]: mask by index (s<=t), max, sum-exp, write P bf16. One row per block.
__global__ __launch_bounds__(256) void col_softmax(const float* __restrict__ S, u16* __restrict__ P)
{
  const int t = blockIdx.x;
  const long long rowOff = ((long long)blockIdx.y * 2048 + t) * 2048;
  const float* row = S + rowOff;
  u16* prow = P + rowOff;
  const int tid = threadIdx.x;
  const int i0 = tid * 4, i1 = 1024 + tid * 4;

  f32x4 a = *(const f32x4*)(row + i0);
  f32x4 b = *(const f32x4*)(row + i1);
  float v[8];
#pragma unroll
  for (int j = 0; j < 4; ++j) {
    v[j]     = (i0 + j <= t) ? a[j] : -1e30f;  // masked/unwritten entries discarded by index
    v[4 + j] = (i1 + j <= t) ? b[j] : -1e30f;
  }
  float m = v[0];
#pragma unroll
  for (int j = 1; j < 8; ++j) m = fmaxf(m, v[j]);
#pragma unroll
  for (int off = 32; off; off >>= 1) m = fmaxf(m, __shfl_xor(m, off));
  __shared__ float red[4];
  __shared__ float red2[4];
  if ((tid & 63) == 0) red[tid >> 6] = m;
  __syncthreads();
  m = fmaxf(fmaxf(red[0], red[1]), fmaxf(red[2], red[3]));

  float e[8]; float ssum = 0.f;
#pragma unroll
  for (int j = 0; j < 8; ++j) { e[j] = __expf(v[j] - m); ssum += e[j]; }
#pragma unroll
  for (int off = 32; off; off >>= 1) ssum += __shfl_xor(ssum, off);
  if ((tid & 63) == 0) red2[tid >> 6] = ssum;
  __syncthreads();
  ssum = red2[0] + red2[1] + red2[2] + red2[3];
  const float inv = 1.0f / ssum;
  u16x4 o0, o1;
#pragma unroll
  for (int j = 0; j < 4; ++j) { o0[j] = f2bf(e[j] * inv); o1[j] = f2bf(e[4 + j] * inv); }
  *(u16x4*)(prow + i0) = o0;
  *(u16x4*)(prow + i1) = o1;
}

extern "C" void kernel_launch(void* const* d_in, const int* in_sizes, int n_in,
                              void* d_out, int out_size, void* d_ws, size_t ws_size,
                              hipStream_t stream)
{
  const float* Q  = (const float*)d_in[0];
  const float* K  = (const float*)d_in[1];
  const float* V  = (const float*)d_in[2];
  const float* WQ = (const float*)d_in[3];
  const float* WK = (const float*)d_in[4];
  const float* WV = (const float*)d_in[5];
  float* out = (float*)d_out;

  const size_t MB = 1ull << 20;
  char* w = (char*)d_ws;
  if (ws_size < 262 * MB) {
    fprintf(stderr, "kernel_launch: workspace too small (%zu B, need >= %zu B)\n",
            ws_size, (size_t)(262 * MB));
    return;
  }

  // ws layout (MB): [0,6) weights bf16 | [6,70) Qd_t | [70,134) Kd_t | [134,198) Vd
  // [198, ...) transient: transposed-input buffer (64MB), later S(fp32)+P(bf16) chunks
  u16* wq    = (u16*)(w + 0 * MB);
  u16* wk    = (u16*)(w + 2 * MB);
  u16* wv    = (u16*)(w + 4 * MB);
  u16* qdt   = (u16*)(w + 6 * MB);
  u16* kdt   = (u16*)(w + 70 * MB);
  u16* vd    = (u16*)(w + 134 * MB);
  u16* trans = (u16*)(w + 198 * MB);
  float* S   = (float*)(w + 198 * MB);

  long long freeMB = (long long)(ws_size / MB) - 198;
  int chunk = (int)(freeMB / 24);  // 16MB S + 8MB P per batch
  if (chunk > 8) chunk = 8;
  u16* P = (u16*)(w + (198 + (size_t)chunk * 16) * MB);

  conv_weights<<<dim3(1024, 3), 256, 0, stream>>>(WQ, WK, WV, wq, wk, wv);

  // Projections. Qd_t/Kd_t stored (b, seq, o) = one (32768 x 1024) GEMM each;
  // Vd stored (b, o, seq), per-batch z.
  conv_transpose<<<dim3(32, 16, 16), dim3(64, 4), 0, stream>>>(Q, trans);
  gemm_bt<true, false, false><<<dim3(8, 128, 1), 512, 0, stream>>>(
      trans, wq, qdt, 1024, 1024, 1024, 1024, 0, 0, 0, 1.0f);
  conv_transpose<<<dim3(32, 16, 16), dim3(64, 4), 0, stream>>>(K, trans);
  gemm_bt<true, false, false><<<dim3(8, 128, 1), 512, 0, stream>>>(
      trans, wk, kdt, 1024, 1024, 1024, 1024, 0, 0, 0, 1.0f);
  conv_transpose<<<dim3(32, 16, 16), dim3(64, 4), 0, stream>>>(V, trans);
  gemm_bt<true, false, false><<<dim3(16, 4, 16), 512, 0, stream>>>(
      wv, trans, vd, 1024, 1024, 1024, 2048,
      0, (long long)2048 * 1024, (long long)1024 * 2048, 1.0f);

  // Attention per batch-chunk: S'[t,s] = Kd_t[t,:]·Qd_t[s,:]/32 (skip s>t tiles),
  // row-softmax over s (masked by index), out[o,t] = sum_s Vd[o,s] P[t,s].
  for (int b0 = 0; b0 < 16; b0 += chunk) {
    const int nb = (16 - b0) < chunk ? (16 - b0) : chunk;
    gemm_bt<false, true, false><<<dim3(16, 8, nb), 512, 0, stream>>>(
        kdt + (long long)b0 * 2048 * 1024, qdt + (long long)b0 * 2048 * 1024, S,
        1024, 1024, 1024, 2048,
        (long long)2048 * 1024, (long long)2048 * 1024, (long long)2048 * 2048, 0.03125f);
    col_softmax<<<dim3(2048, nb), 256, 0, stream>>>(S, P);
    gemm_bt<false, false, true><<<dim3(16, 4, nb), 512, 0, stream>>>(
        vd + (long long)b0 * 1024 * 2048, P, out + (long long)b0 * 1024 * 2048,
        2048, 2048, 2048, 2048,
        (long long)1024 * 2048, (long long)2048 * 2048, (long long)1024 * 2048, 1.0f);
  }
}

// Round 6
// 682.010 us; speedup vs baseline: 1.4160x; 1.0921x over previous
//
#include <hip/hip_runtime.h>
#include <cstdio>
#include <math.h>

typedef unsigned short u16;
typedef float f32x4 __attribute__((ext_vector_type(4)));
typedef __bf16 bf16x8 __attribute__((ext_vector_type(8)));
typedef u16 u16x4 __attribute__((ext_vector_type(4)));
typedef u16 u16x8 __attribute__((ext_vector_type(8)));

__device__ __forceinline__ u16 f2bf(float x) {
  unsigned u = __float_as_uint(x);
  u = (u + 0x7FFFu + ((u >> 16) & 1u)) >> 16;
  return (u16)u;
}
__device__ __forceinline__ float bf2f(u16 x) {
  return __uint_as_float(((unsigned)x) << 16);
}

__device__ __forceinline__ f32x4 mfma_bf16(bf16x8 a, bf16x8 b, f32x4 c) {
  return __builtin_amdgcn_mfma_f32_16x16x32_bf16(a, b, c, 0, 0, 0);
}

// async global->LDS, 16B per lane. LDS dest = wave-uniform base + lane*16.
__device__ __forceinline__ void gload_lds16(const void* g, void* l) {
  __builtin_amdgcn_global_load_lds(
      (const __attribute__((address_space(1))) void*)g,
      (__attribute__((address_space(3))) void*)l, 16, 0, 0);
}

// C[m,n] = scale * sum_k A[m,k] * B[n,k]   (both operands K-contiguous)
// BM=256 x BN=128, BK=64. 512 threads = 8 waves (4M x 2N), per-wave 64x64 out.
// TRIPLE-buffered LDS (48KB/buf), counted vmcnt(6) at tile boundaries (T4),
// 16B-slot XOR swizzle via pre-swizzled global source (T2, conflicts==0).
// Block-index modes (causal work must be XCD-BALANCED, r5 lesson):
//  XSWZ: T1 XCD swizzle for UNIFORM grids (proj) — contiguous chunk per XCD.
//  TRI:  compact causal launch: gridDim.x == 72 == #live tiles of the 8x16
//        (256-row x 128-col) triangular tiling; decode j->(by,bx), bx<=2by+1.
//        Equal work per tile -> default round-robin balances XCDs (72%8==0).
//  SWAPXY: bx=blockIdx.y, by=blockIdx.x — for PV/KLIMIT, puts the variable-
//        work dim on y so round-robin interleaves it across XCDs (1.1x skew).
template <bool BF16OUT, bool XSWZ, bool TRI, bool KLIMIT, bool SWAPXY>
__global__ __launch_bounds__(512, 2) void gemm_bt(
    const u16* __restrict__ A, const u16* __restrict__ B, void* __restrict__ Cv,
    int K, int lda, int ldb, int ldc,
    long long sAz, long long sBz, long long sCz, float scale)
{
  int bx, by;
  if (TRI) {
    const int j = blockIdx.x;
    int r = (int)(0.5f * (sqrtf(4.f * j + 1.f) - 1.f));
    while (r * (r + 1) > j) --r;
    while ((r + 1) * (r + 2) <= j) ++r;
    by = r;
    bx = j - r * (r + 1);
  } else if (SWAPXY) {
    bx = blockIdx.y; by = blockIdx.x;
  } else if (XSWZ) {
    const int gx = gridDim.x;
    const int nwg = gx * gridDim.y;
    const int f0 = blockIdx.x + gx * blockIdx.y;
    const int f = (f0 & 7) * (nwg >> 3) + (f0 >> 3);
    bx = f & (gx - 1);
    by = f / gx;
  } else {
    bx = blockIdx.x; by = blockIdx.y;
  }

  const int n0 = bx * 128;
  const int m0 = by * 256;
  const int z = blockIdx.z;
  A += (long long)z * sAz;
  B += (long long)z * sBz;

  const int tid = threadIdx.x;
  const int wave = tid >> 6, lane = tid & 63;
  const int wr = wave >> 1, wc = wave & 1;  // 4M x 2N wave grid

  // per buffer: A [256][64] u16 at 0, B [128][64] u16 at 16384; 24576 u16 = 48KB
  __shared__ u16 lds[3][24576];

  f32x4 acc[4][4] = {};

  int kEnd = K;
  if (KLIMIT) { int ke = n0 + 128; kEnd = ke < K ? ke : K; }  // P[t,s]==0 for s>t
  const int nt = kEnd >> 6;  // always >= 2 for our launches

  // ---- staging geometry: chunk c covers rows c*8..c*8+7; lane -> row c*8+(lane>>3),
  // phys 16B slot lane&7. Pre-swizzle SOURCE so LDS stays linear:
  // logical slot = phys ^ (row&7); (c*8)&7==0 so row&7 == (lane>>3)&7.
  const int sOff = ((lane & 7) ^ ((lane >> 3) & 7)) * 8;  // element offset
  const u16* gAs = A + (long long)(m0 + (lane >> 3)) * lda + sOff;
  const u16* gBs = B + (long long)(n0 + (lane >> 3)) * ldb + sOff;

  // ---- read geometry: logical (row r, slot s) lives at phys slot s^(r&7).
  const int frow = lane & 15, g = lane >> 4, swz = frow & 7;
  const int aoff0 = (wr * 64 + frow) * 64 + ((g    ) ^ swz) * 8;   // kk=0
  const int aoff1 = (wr * 64 + frow) * 64 + ((4 + g) ^ swz) * 8;   // kk=32
  const int boff0 = 16384 + (wc * 64 + frow) * 64 + ((g    ) ^ swz) * 8;
  const int boff1 = 16384 + (wc * 64 + frow) * 64 + ((4 + g) ^ swz) * 8;

#define STAGE_A(T, BUF)                                                        \
  {                                                                            \
    const long long kc = (long long)(T) * 64;                                  \
    _Pragma("unroll")                                                          \
    for (int j = 0; j < 4; ++j) {                                              \
      const int c = j * 8 + wave;                                              \
      gload_lds16(gAs + (long long)(c * 8) * lda + kc, &lds[BUF][c * 512]);    \
    }                                                                          \
  }
#define STAGE_B(T, BUF)                                                        \
  {                                                                            \
    const long long kc = (long long)(T) * 64;                                  \
    _Pragma("unroll")                                                          \
    for (int j = 0; j < 2; ++j) {                                              \
      const int c = j * 8 + wave;                                              \
      gload_lds16(gBs + (long long)(c * 8) * ldb + kc,                         \
                  &lds[BUF][16384 + c * 512]);                                 \
    }                                                                          \
  }

  // ---- prologue: stage t0 -> buf0, t1 -> buf1; wait t0 (6 newest = t1 stay in flight)
  STAGE_A(0, 0) STAGE_B(0, 0)
  if (nt > 1) {
    STAGE_A(1, 1) STAGE_B(1, 1)
    asm volatile("s_waitcnt vmcnt(6)" ::: "memory");
  } else {
    asm volatile("s_waitcnt vmcnt(0)" ::: "memory");
  }
  __builtin_amdgcn_s_barrier();

  int cur = 0, nxt = 2;
  for (int t = 0; t < nt; ++t) {
    const u16* bb = &lds[cur][0];
    const bool pf = (t + 2 < nt);
    bf16x8 A0[4], A1[4], B0k0[2], B0k1[2], B1k0[2], B1k1[2];

    // ---- phase 1: ds-read A frags (8) + B n0-1 (4); stage A(t+2); MFMA n0-1
#pragma unroll
    for (int m = 0; m < 4; ++m) {
      A0[m] = *(const bf16x8*)(bb + aoff0 + m * 1024);
      A1[m] = *(const bf16x8*)(bb + aoff1 + m * 1024);
    }
#pragma unroll
    for (int n = 0; n < 2; ++n) {
      B0k0[n] = *(const bf16x8*)(bb + boff0 + n * 1024);
      B0k1[n] = *(const bf16x8*)(bb + boff1 + n * 1024);
    }
    if (pf) STAGE_A(t + 2, nxt)
    __builtin_amdgcn_s_barrier();
    __builtin_amdgcn_s_setprio(1);
#pragma unroll
    for (int m = 0; m < 4; ++m)
#pragma unroll
      for (int n = 0; n < 2; ++n)
        acc[m][n] = mfma_bf16(A0[m], B0k0[n], acc[m][n]);
#pragma unroll
    for (int m = 0; m < 4; ++m)
#pragma unroll
      for (int n = 0; n < 2; ++n)
        acc[m][n] = mfma_bf16(A1[m], B0k1[n], acc[m][n]);
    __builtin_amdgcn_s_setprio(0);
    __builtin_amdgcn_s_barrier();

    // ---- phase 2: ds-read B n2-3 (4, A reused); stage B(t+2); MFMA n2-3
#pragma unroll
    for (int n = 0; n < 2; ++n) {
      B1k0[n] = *(const bf16x8*)(bb + boff0 + (2 + n) * 1024);
      B1k1[n] = *(const bf16x8*)(bb + boff1 + (2 + n) * 1024);
    }
    if (pf) STAGE_B(t + 2, nxt)
    __builtin_amdgcn_s_barrier();
    __builtin_amdgcn_s_setprio(1);
#pragma unroll
    for (int m = 0; m < 4; ++m)
#pragma unroll
      for (int n = 0; n < 2; ++n)
        acc[m][n + 2] = mfma_bf16(A0[m], B1k0[n], acc[m][n + 2]);
#pragma unroll
    for (int m = 0; m < 4; ++m)
#pragma unroll
      for (int n = 0; n < 2; ++n)
        acc[m][n + 2] = mfma_bf16(A1[m], B1k1[n], acc[m][n + 2]);
    __builtin_amdgcn_s_setprio(0);
    // ---- tile boundary: retire t+1's 6 loads; keep t+2's 6 in flight
    if (pf) asm volatile("s_waitcnt vmcnt(6)" ::: "memory");
    else    asm volatile("s_waitcnt vmcnt(0)" ::: "memory");
    __builtin_amdgcn_s_barrier();
    cur = (cur == 2) ? 0 : cur + 1;
    nxt = (nxt == 2) ? 0 : nxt + 1;
  }
#undef STAGE_A
#undef STAGE_B

  // C/D layout: col = lane&15, row = (lane>>4)*4 + r  [m89-verified]
  const int crow0 = m0 + wr * 64 + (lane >> 4) * 4;
  const int ccol0 = n0 + wc * 64 + (lane & 15);
  if (BF16OUT) {
    u16* C = (u16*)Cv + (long long)z * sCz;
#pragma unroll
    for (int m = 0; m < 4; ++m)
#pragma unroll
      for (int n = 0; n < 4; ++n)
#pragma unroll
        for (int r = 0; r < 4; ++r)
          C[(long long)(crow0 + m * 16 + r) * ldc + ccol0 + n * 16] = f2bf(acc[m][n][r] * scale);
  } else {
    float* C = (float*)Cv + (long long)z * sCz;
#pragma unroll
    for (int m = 0; m < 4; ++m)
#pragma unroll
      for (int n = 0; n < 4; ++n)
#pragma unroll
        for (int r = 0; r < 4; ++r)
          C[(long long)(crow0 + m * 16 + r) * ldc + ccol0 + n * 16] = acc[m][n][r] * scale;
  }
}

// (b, i, s) fp32  ->  (b, s, i) bf16 ; one 64x64 tile per block, block (64,4)
__global__ __launch_bounds__(256) void conv_transpose(const float* __restrict__ src, u16* __restrict__ dst)
{
  const int b = blockIdx.z;
  const float* s = src + (long long)b * 1024 * 2048;
  u16* d = dst + (long long)b * 2048 * 1024;
  const int s0 = blockIdx.x * 64, i0 = blockIdx.y * 64;
  const int tx = threadIdx.x, ty = threadIdx.y;
  __shared__ float tile[64][65];
#pragma unroll
  for (int r = 0; r < 16; ++r)
    tile[r * 4 + ty][tx] = s[(long long)(i0 + r * 4 + ty) * 2048 + s0 + tx];
  __syncthreads();
#pragma unroll
  for (int r = 0; r < 16; ++r)
    d[(long long)(s0 + r * 4 + ty) * 1024 + i0 + tx] = f2bf(tile[tx][r * 4 + ty]);
}

__global__ __launch_bounds__(256) void conv_weights(
    const float* __restrict__ a, const float* __restrict__ b, const float* __restrict__ c,
    u16* __restrict__ oa, u16* __restrict__ ob, u16* __restrict__ oc)
{
  const int which = blockIdx.y;
  const float* s = which == 0 ? a : which == 1 ? b : c;
  u16* d = which == 0 ? oa : which == 1 ? ob : oc;
  const int idx = (blockIdx.x * 256 + threadIdx.x) * 4;
  f32x4 v = *(const f32x4*)(s + idx);
  u16x4 o;
#pragma unroll
  for (int j = 0; j < 4; ++j) o[j] = f2bf(v[j]);
  *(u16x4*)(d + idx) = o;
}

// Row t of S'[t,s] (bf16 in): mask by index (s<=t), max, sum-exp, write P bf16.
// One row per block; 256 threads x 8 elems = 2048.
__global__ __launch_bounds__(256) void col_softmax(const u16* __restrict__ S, u16* __restrict__ P)
{
  const int t = blockIdx.x;
  const long long rowOff = ((long long)blockIdx.y * 2048 + t) * 2048;
  const u16* row = S + rowOff;
  u16* prow = P + rowOff;
  const int tid = threadIdx.x;
  const int i0 = tid * 8;

  u16x8 a = *(const u16x8*)(row + i0);
  float v[8];
#pragma unroll
  for (int j = 0; j < 8; ++j)
    v[j] = (i0 + j <= t) ? bf2f(a[j]) : -1e30f;  // unwritten/masked discarded by index

  float m = v[0];
#pragma unroll
  for (int j = 1; j < 8; ++j) m = fmaxf(m, v[j]);
#pragma unroll
  for (int off = 32; off; off >>= 1) m = fmaxf(m, __shfl_xor(m, off));
  __shared__ float red[4];
  __shared__ float red2[4];
  if ((tid & 63) == 0) red[tid >> 6] = m;
  __syncthreads();
  m = fmaxf(fmaxf(red[0], red[1]), fmaxf(red[2], red[3]));

  float e[8]; float ssum = 0.f;
#pragma unroll
  for (int j = 0; j < 8; ++j) { e[j] = __expf(v[j] - m); ssum += e[j]; }
#pragma unroll
  for (int off = 32; off; off >>= 1) ssum += __shfl_xor(ssum, off);
  if ((tid & 63) == 0) red2[tid >> 6] = ssum;
  __syncthreads();
  ssum = red2[0] + red2[1] + red2[2] + red2[3];
  const float inv = 1.0f / ssum;
  u16x8 o;
#pragma unroll
  for (int j = 0; j < 8; ++j) o[j] = f2bf(e[j] * inv);
  *(u16x8*)(prow + i0) = o;
}

extern "C" void kernel_launch(void* const* d_in, const int* in_sizes, int n_in,
                              void* d_out, int out_size, void* d_ws, size_t ws_size,
                              hipStream_t stream)
{
  const float* Q  = (const float*)d_in[0];
  const float* K  = (const float*)d_in[1];
  const float* V  = (const float*)d_in[2];
  const float* WQ = (const float*)d_in[3];
  const float* WK = (const float*)d_in[4];
  const float* WV = (const float*)d_in[5];
  float* out = (float*)d_out;

  const size_t MB = 1ull << 20;
  char* w = (char*)d_ws;
  if (ws_size < 262 * MB) {
    fprintf(stderr, "kernel_launch: workspace too small (%zu B, need >= %zu B)\n",
            ws_size, (size_t)(262 * MB));
    return;
  }

  // ws layout (MB): [0,6) weights bf16 | [6,70) Qd_t | [70,134) Kd_t | [134,198) Vd
  // [198, ...) transient: transposed-input buffer (64MB), later S(bf16)+P(bf16) chunks
  u16* wq    = (u16*)(w + 0 * MB);
  u16* wk    = (u16*)(w + 2 * MB);
  u16* wv    = (u16*)(w + 4 * MB);
  u16* qdt   = (u16*)(w + 6 * MB);
  u16* kdt   = (u16*)(w + 70 * MB);
  u16* vd    = (u16*)(w + 134 * MB);
  u16* trans = (u16*)(w + 198 * MB);
  u16* S     = (u16*)(w + 198 * MB);

  long long freeMB = (long long)(ws_size / MB) - 198;
  int chunk = (int)(freeMB / 16);  // 8MB S + 8MB P per batch (both bf16)
  if (chunk > 8) chunk = 8;
  u16* P = (u16*)(w + (198 + (size_t)chunk * 8) * MB);

  conv_weights<<<dim3(1024, 3), 256, 0, stream>>>(WQ, WK, WV, wq, wk, wv);

  // Projections. Qd_t/Kd_t stored (b, seq, o) = one (32768 x 1024) GEMM each;
  // Vd stored (b, o, seq), per-batch z. Uniform grids -> XCD swizzle (T1).
  conv_transpose<<<dim3(32, 16, 16), dim3(64, 4), 0, stream>>>(Q, trans);
  gemm_bt<true, true, false, false, false><<<dim3(8, 128, 1), 512, 0, stream>>>(
      trans, wq, qdt, 1024, 1024, 1024, 1024, 0, 0, 0, 1.0f);
  conv_transpose<<<dim3(32, 16, 16), dim3(64, 4), 0, stream>>>(K, trans);
  gemm_bt<true, true, false, false, false><<<dim3(8, 128, 1), 512, 0, stream>>>(
      trans, wk, kdt, 1024, 1024, 1024, 1024, 0, 0, 0, 1.0f);
  conv_transpose<<<dim3(32, 16, 16), dim3(64, 4), 0, stream>>>(V, trans);
  gemm_bt<true, true, false, false, false><<<dim3(16, 4, 16), 512, 0, stream>>>(
      wv, trans, vd, 1024, 1024, 1024, 2048,
      0, (long long)2048 * 1024, (long long)1024 * 2048, 1.0f);

  // Attention per batch-chunk:
  //  S'[t,s] = Kd_t[t,:]·Qd_t[s,:]/32 — compact triangular grid (72 live tiles/z)
  //  row-softmax over s (masked by index), S/P bf16
  //  out[o,t] = sum_s Vd[o,s] P[t,s] — KLIMIT, swapped grid for XCD balance
  for (int b0 = 0; b0 < 16; b0 += chunk) {
    const int nb = (16 - b0) < chunk ? (16 - b0) : chunk;
    gemm_bt<true, false, true, false, false><<<dim3(72, 1, nb), 512, 0, stream>>>(
        kdt + (long long)b0 * 2048 * 1024, qdt + (long long)b0 * 2048 * 1024, S,
        1024, 1024, 1024, 2048,
        (long long)2048 * 1024, (long long)2048 * 1024, (long long)2048 * 2048, 0.03125f);
    col_softmax<<<dim3(2048, nb), 256, 0, stream>>>(S, P);
    gemm_bt<false, false, false, true, true><<<dim3(4, 16, nb), 512, 0, stream>>>(
        vd + (long long)b0 * 1024 * 2048, P, out + (long long)b0 * 1024 * 2048,
        2048, 2048, 2048, 2048,
        (long long)1024 * 2048, (long long)2048 * 2048, (long long)1024 * 2048, 1.0f);
  }
}